// Round 14
// baseline (747.187 us; speedup 1.0000x reference)
//
#include <hip/hip_runtime.h>

typedef __attribute__((ext_vector_type(4))) float f32x4;
typedef __attribute__((ext_vector_type(8))) __bf16 bf16x8;
typedef __attribute__((ext_vector_type(8))) unsigned short us8;
typedef unsigned short u16;

#define SSILU_SCALE (1.0f / 0.6f)
#define INV_SQRT2 0.70710678118654752f

__device__ __forceinline__ u16 f2bf(float f) {
    __bf16 h = (__bf16)f;
    return __builtin_bit_cast(u16, h);
}
__device__ __forceinline__ float bf2f(u16 h) {
    union { unsigned int u; float f; } v; v.u = ((unsigned int)h) << 16;
    return v.f;
}
__device__ __forceinline__ float ssilu(float x) {
    float e = __expf(-x);
    float s = __builtin_amdgcn_rcpf(1.0f + e);
    return x * s * SSILU_SCALE;
}

// ---------------------------------------------------------------------------
// prep: (unchanged layouts)
//  WinF : W_in as B-fragments [kt20][w4][kk2][n4][lane64][8]
//  Wfrag: 4 resid matrices as [g][w4][kk8][n4][lane64][8]
// ---------------------------------------------------------------------------
__global__ __launch_bounds__(256) void prep_kernel(
    const float* __restrict__ Win, const float* __restrict__ W1a,
    const float* __restrict__ W1b, const float* __restrict__ W2a,
    const float* __restrict__ W2b, u16* __restrict__ WinF,
    u16* __restrict__ Wfrag, float* __restrict__ out, int outN) {
    int i = blockIdx.x * 256 + threadIdx.x;
    if (i < 327680) {
        int e = i & 7, lane = (i >> 3) & 63, n = (i >> 9) & 3;
        int kk = (i >> 11) & 1, w = (i >> 12) & 3, kt = i >> 14;
        int lo = lane & 15, hi = lane >> 4;
        int k = kt * 64 + kk * 32 + hi * 8 + e;
        int col = w * 64 + n * 16 + lo;
        WinF[i] = f2bf(Win[k * 256 + col]);
        return;
    }
    int j = i - 327680;
    if (j < 262144) {
        int g = j >> 16, r = j & 65535;
        int chunk = r >> 9, within = r & 511;
        int lane = within >> 3, e = within & 7;
        int w = chunk >> 5, kk = (chunk >> 2) & 7, n = chunk & 3;
        int lo = lane & 15, hi = lane >> 4;
        int col = w * 64 + n * 16 + lo;
        int k = kk * 32 + hi * 8 + e;
        const float* W = (g == 0) ? W1a : (g == 1) ? W1b : (g == 2) ? W2a : W2b;
        Wfrag[j] = f2bf(W[k * 256 + col]);
        return;
    }
    int z = j - 262144;
    if (z < outN) out[z] = 0.0f;
}

// ---------------------------------------------------------------------------
// fused_pc: persistent producer/consumer. 1 block/CU, 512 threads (8 waves).
// Waves 0-3 (producer): phase-1 GEMM of tile s -> xb[s&1]  (R6 BK=64 pipe).
// Waves 4-7 (consumer): phase-2 residual stack of tile s-1 on xb[(s-1)&1]
// (R13 3-set rotating B). Exactly 22 s_barriers per stage per role.
// ---------------------------------------------------------------------------
__global__ __launch_bounds__(512, 1) void fused_pc(
    const float* __restrict__ A, const u16* __restrict__ WinF,
    const u16* __restrict__ Wfrag, const float* __restrict__ Wout,
    const float* __restrict__ evec, const int* __restrict__ eidx,
    float* __restrict__ out, int ntiles) {
    __shared__ u16 xb[2][64 * 256];   // 2 x 32KB x-tiles (parity)
    __shared__ u16 As[2][64 * 64];    // 2 x 8KB producer A dbuf
    __shared__ u16 tb[64 * 256];      // 32KB consumer t1 buffer
    __shared__ float fpart[4][64];
    const int tid = threadIdx.x;
    const int role = __builtin_amdgcn_readfirstlane(tid >> 8);
    const int t = tid & 255;
    const int w = t >> 6, l = t & 63;
    const int lo = l & 15, hi = l >> 4;
    const int swz = (lo & 7) << 4;
    const int bid = blockIdx.x;
    const int NT = (ntiles - bid + 255) / 256;   // tiles: bid + 256*i

    auto BAR = []() { __builtin_amdgcn_s_barrier(); };
    auto FENCE = []() {
        asm volatile("s_waitcnt lgkmcnt(0)" ::: "memory");
        __builtin_amdgcn_sched_barrier(0);
        __builtin_amdgcn_s_barrier();
    };

    if (role == 0) {
        // ===================== PRODUCER (waves 0-3) =====================
        char* As0 = (char*)As[0];
        char* As1 = (char*)As[1];
        const u16* WinFw = WinF + w * 4096 + l * 8;
        for (int s = 0; s <= NT; ++s) {
            if (s >= NT) {                 // drain stage: pad 22 barriers
                for (int k = 0; k < 22; ++k) BAR();
                continue;
            }
            const long rowbase = (long)(bid + 256 * s) * 64;
            char* xbp = (char*)xb[s & 1];

            f32x4 acc[4][4];
#pragma unroll
            for (int m = 0; m < 4; m++)
#pragma unroll
                for (int n = 0; n < 4; n++) acc[m][n] = (f32x4){0.f, 0.f, 0.f, 0.f};

            float4 va[2][2];
            auto LOADA = [&](int kb) {
#pragma unroll
                for (int c = 0; c < 2; ++c) {
                    int idx = t + c * 256;
                    int r = idx >> 3, k8 = (idx & 7) * 8;
                    const float* sp = A + (rowbase + r) * 1280 + kb + k8;
                    va[c][0] = *(const float4*)sp;
                    va[c][1] = *(const float4*)(sp + 4);
                }
            };
            auto WRITEA = [&](char* dst) {
#pragma unroll
                for (int c = 0; c < 2; ++c) {
                    int idx = t + c * 256;
                    int r = idx >> 3, k8 = (idx & 7) * 8;
                    us8 p;
                    p[0] = f2bf(va[c][0].x); p[1] = f2bf(va[c][0].y);
                    p[2] = f2bf(va[c][0].z); p[3] = f2bf(va[c][0].w);
                    p[4] = f2bf(va[c][1].x); p[5] = f2bf(va[c][1].y);
                    p[6] = f2bf(va[c][1].z); p[7] = f2bf(va[c][1].w);
                    *(us8*)(dst + r * 128 + ((k8 * 2) ^ ((r & 7) << 4))) = p;
                }
            };
            auto LOADB = [&](int kt, int kk, bf16x8 (&b)[4]) {
                const u16* base = WinFw + kt * 16384 + kk * 2048;
#pragma unroll
                for (int n = 0; n < 4; ++n)
                    b[n] = __builtin_bit_cast(bf16x8, *(const us8*)(base + n * 512));
            };
            auto MFMA_KK = [&](const char* AB, int kk, const bf16x8 (&bc)[4]) {
                int kbyte = kk * 64 + hi * 16;
                bf16x8 af[4];
#pragma unroll
                for (int m = 0; m < 4; m++) {
                    int r = m * 16 + lo;
                    af[m] = __builtin_bit_cast(bf16x8,
                        *(const us8*)(AB + r * 128 + (kbyte ^ swz)));
                }
#pragma unroll
                for (int m = 0; m < 4; m++)
#pragma unroll
                    for (int n = 0; n < 4; n++)
                        acc[m][n] = __builtin_amdgcn_mfma_f32_16x16x32_bf16(
                            af[m], bc[n], acc[m][n], 0, 0, 0);
            };

            bf16x8 bc[4], bn[4];
            // prologue (BAR 1)
            LOADA(0);
            WRITEA(As0);
            LOADB(0, 0, bc);
            LOADA(64);
            FENCE();
            // 20 steps (BARs 2..21)
            for (int kt = 0; kt < 20; ++kt) {
                const char* AScur = (kt & 1) ? As1 : As0;
                char* ASnxt = (kt & 1) ? As0 : As1;
                const bool more = (kt < 19);
                LOADB(kt, 1, bn);
                MFMA_KK(AScur, 0, bc);
                if (more) LOADB(kt + 1, 0, bc);
                MFMA_KK(AScur, 1, bn);
                if (more) WRITEA(ASnxt);
                if (kt <= 17) LOADA((kt + 2) * 64);
                FENCE();
            }
            // epilogue: x = ssilu(acc) -> xb[s&1]  (BAR 22)
#pragma unroll
            for (int m = 0; m < 4; m++)
#pragma unroll
                for (int n = 0; n < 4; n++)
#pragma unroll
                    for (int j = 0; j < 4; j++) {
                        int r = m * 16 + hi * 4 + j;
                        int cc = w * 64 + n * 16 + lo;
                        *(u16*)(xbp + r * 512 + ((cc * 2) ^ ((r & 7) << 4))) =
                            f2bf(ssilu(acc[m][n][j]));
                    }
            FENCE();
        }
    } else {
        // ===================== CONSUMER (waves 4-7) =====================
        char* tbB = (char*)tb;
        const u16* Wfw = Wfrag + w * 16384;
        float wo[4];
#pragma unroll
        for (int n = 0; n < 4; n++) wo[n] = Wout[w * 64 + n * 16 + lo];

        for (int s = 0; s <= NT; ++s) {
            if (s == 0) {                  // fill stage: pad 22 barriers
                for (int k = 0; k < 22; ++k) BAR();
                continue;
            }
            const long rowbase = (long)(bid + 256 * (s - 1)) * 64;
            char* xbp = (char*)xb[(s - 1) & 1];

            f32x4 acc[4][4];
            bf16x8 b0[4], b1[4], b2[4];
            auto LW = [&](const u16* Wg, int kk, bf16x8 (&b)[4]) {
                const u16* base = Wg + kk * 2048 + l * 8;
#pragma unroll
                for (int n = 0; n < 4; ++n)
                    b[n] = __builtin_bit_cast(bf16x8, *(const us8*)(base + n * 512));
            };
            auto GEMM = [&](const char* AB, const u16* Wg) {
#pragma unroll
                for (int m = 0; m < 4; m++)
#pragma unroll
                    for (int n = 0; n < 4; n++) acc[m][n] = (f32x4){0.f, 0.f, 0.f, 0.f};
#pragma unroll
                for (int kk = 0; kk < 8; ++kk) {
                    if (kk < 6) {
                        const int st = (kk + 2) % 3;
                        if (st == 0)      LW(Wg, kk + 2, b0);
                        else if (st == 1) LW(Wg, kk + 2, b1);
                        else              LW(Wg, kk + 2, b2);
                    }
                    int kbyte = kk * 64 + hi * 16;
                    bf16x8 af[4];
#pragma unroll
                    for (int m = 0; m < 4; m++) {
                        int r = m * 16 + lo;
                        af[m] = __builtin_bit_cast(bf16x8,
                            *(const us8*)(AB + r * 512 + (kbyte ^ ((r & 7) << 4))));
                    }
                    const bf16x8 (&bu)[4] = (kk % 3 == 0) ? b0 : (kk % 3 == 1) ? b1 : b2;
#pragma unroll
                    for (int m = 0; m < 4; m++)
#pragma unroll
                        for (int n = 0; n < 4; n++)
                            acc[m][n] = __builtin_amdgcn_mfma_f32_16x16x32_bf16(
                                af[m], bu[n], acc[m][n], 0, 0, 0);
                }
            };

            // BAR 1: preload G1's b0/b1 (xb[(s-1)&1] ready since last stage)
            LW(Wfw + 0 * 65536, 0, b0);
            LW(Wfw + 0 * 65536, 1, b1);
            BAR();

            // G1: t1 = ssilu(x @ W1a) -> tb      (BAR 2)
            GEMM(xbp, Wfw + 0 * 65536);
#pragma unroll
            for (int m = 0; m < 4; m++)
#pragma unroll
                for (int n = 0; n < 4; n++)
#pragma unroll
                    for (int j = 0; j < 4; j++) {
                        int r = m * 16 + hi * 4 + j;
                        int cc = w * 64 + n * 16 + lo;
                        *(u16*)(tbB + r * 512 + ((cc * 2) ^ ((r & 7) << 4))) =
                            f2bf(ssilu(acc[m][n][j]));
                    }
            LW(Wfw + 1 * 65536, 0, b0);
            LW(Wfw + 1 * 65536, 1, b1);
            FENCE();

            // G2: x = (x + ssilu(t1 @ W1b)) * INV_SQRT2 -> xb (in place) (BAR 3)
            GEMM(tbB, Wfw + 1 * 65536);
#pragma unroll
            for (int m = 0; m < 4; m++)
#pragma unroll
                for (int n = 0; n < 4; n++)
#pragma unroll
                    for (int j = 0; j < 4; j++) {
                        int r = m * 16 + hi * 4 + j;
                        int cc = w * 64 + n * 16 + lo;
                        char* p = xbp + r * 512 + ((cc * 2) ^ ((r & 7) << 4));
                        float xn = (bf2f(*(u16*)p) + ssilu(acc[m][n][j])) * INV_SQRT2;
                        *(u16*)p = f2bf(xn);
                    }
            LW(Wfw + 2 * 65536, 0, b0);
            LW(Wfw + 2 * 65536, 1, b1);
            FENCE();

            // G3: t1 = ssilu(x @ W2a) -> tb      (BAR 4)
            GEMM(xbp, Wfw + 2 * 65536);
#pragma unroll
            for (int m = 0; m < 4; m++)
#pragma unroll
                for (int n = 0; n < 4; n++)
#pragma unroll
                    for (int j = 0; j < 4; j++) {
                        int r = m * 16 + hi * 4 + j;
                        int cc = w * 64 + n * 16 + lo;
                        *(u16*)(tbB + r * 512 + ((cc * 2) ^ ((r & 7) << 4))) =
                            f2bf(ssilu(acc[m][n][j]));
                    }
            LW(Wfw + 3 * 65536, 0, b0);
            LW(Wfw + 3 * 65536, 1, b1);
            FENCE();

            // G4 + W_out dot + fpart             (BAR 5)
            GEMM(tbB, Wfw + 3 * 65536);
            float part[4][4];
#pragma unroll
            for (int m = 0; m < 4; m++)
#pragma unroll
                for (int j = 0; j < 4; j++) part[m][j] = 0.f;
#pragma unroll
            for (int m = 0; m < 4; m++)
#pragma unroll
                for (int n = 0; n < 4; n++)
#pragma unroll
                    for (int j = 0; j < 4; j++) {
                        int r = m * 16 + hi * 4 + j;
                        int cc = w * 64 + n * 16 + lo;
                        const char* p = xbp + r * 512 + ((cc * 2) ^ ((r & 7) << 4));
                        float xf = (bf2f(*(const u16*)p) + ssilu(acc[m][n][j])) * INV_SQRT2;
                        part[m][j] += xf * wo[n];
                    }
#pragma unroll
            for (int m = 0; m < 4; m++)
#pragma unroll
                for (int j = 0; j < 4; j++) {
                    float v = part[m][j];
                    v += __shfl_xor(v, 1);
                    v += __shfl_xor(v, 2);
                    v += __shfl_xor(v, 4);
                    v += __shfl_xor(v, 8);
                    if (lo == 0) fpart[w][m * 16 + hi * 4 + j] = v;
                }
            FENCE();

            // scatter-add (reads fpart after BAR 5)
            if (t < 64) {
                int r = t;
                float F = fpart[0][r] + fpart[1][r] + fpart[2][r] + fpart[3][r];
                long e = rowbase + r;
                float vx = evec[e * 3 + 0], vy = evec[e * 3 + 1], vz = evec[e * 3 + 2];
                int a = eidx[e];
                atomicAdd(&out[a * 3 + 0], F * vx);
                atomicAdd(&out[a * 3 + 1], F * vy);
                atomicAdd(&out[a * 3 + 2], F * vz);
            }
            // pad to 22 barriers (BARs 6..22)
            for (int k = 0; k < 17; ++k) BAR();
        }
    }
}

extern "C" void kernel_launch(void* const* d_in, const int* in_sizes, int n_in,
                              void* d_out, int out_size, void* d_ws, size_t ws_size,
                              hipStream_t stream) {
    const float* x_cat = (const float*)d_in[0];
    const float* evec  = (const float*)d_in[1];
    const int*   eidx  = (const int*)d_in[2];
    const float* Win   = (const float*)d_in[3];
    const float* W1a   = (const float*)d_in[4];
    const float* W1b   = (const float*)d_in[5];
    const float* W2a   = (const float*)d_in[6];
    const float* W2b   = (const float*)d_in[7];
    const float* Wout  = (const float*)d_in[8];
    float* out = (float*)d_out;
    const int E = in_sizes[1] / 3;   // 200000
    const int ntiles = E / 64;       // 3125

    u16* WinF  = (u16*)d_ws;          // 327680 elems
    u16* Wfrag = WinF + 327680;       // 262144 elems

    int prepN = 327680 + 262144 + out_size;
    prep_kernel<<<(prepN + 255) / 256, 256, 0, stream>>>(
        Win, W1a, W1b, W2a, W2b, WinF, Wfrag, out, out_size);
    fused_pc<<<256, 512, 0, stream>>>(
        x_cat, WinF, Wfrag, Wout, evec, eidx, out, ntiles);
}

// Round 15
// 376.880 us; speedup vs baseline: 1.9826x; 1.9826x over previous
//
#include <hip/hip_runtime.h>

typedef __attribute__((ext_vector_type(4))) float f32x4;
typedef __attribute__((ext_vector_type(8))) __bf16 bf16x8;
typedef __attribute__((ext_vector_type(8))) unsigned short us8;
typedef unsigned short u16;

#define SSILU_SCALE (1.0f / 0.6f)
#define INV_SQRT2 0.70710678118654752f

__device__ __forceinline__ u16 f2bf(float f) {
    __bf16 h = (__bf16)f;
    return __builtin_bit_cast(u16, h);
}
__device__ __forceinline__ float bf2f(u16 h) {
    union { unsigned int u; float f; } v; v.u = ((unsigned int)h) << 16;
    return v.f;
}
__device__ __forceinline__ float ssilu(float x) {
    float e = __expf(-x);
    float s = __builtin_amdgcn_rcpf(1.0f + e);
    return x * s * SSILU_SCALE;
}

// ---------------------------------------------------------------------------
// prep: (unchanged layouts)
//  WinF : W_in as B-fragments [kt20][w4][kk2][n4][lane64][8]
//  Wfrag: 4 resid matrices as [g][w4][kk8][n4][lane64][8]
// ---------------------------------------------------------------------------
__global__ __launch_bounds__(256) void prep_kernel(
    const float* __restrict__ Win, const float* __restrict__ W1a,
    const float* __restrict__ W1b, const float* __restrict__ W2a,
    const float* __restrict__ W2b, u16* __restrict__ WinF,
    u16* __restrict__ Wfrag, float* __restrict__ out, int outN) {
    int i = blockIdx.x * 256 + threadIdx.x;
    if (i < 327680) {
        int e = i & 7, lane = (i >> 3) & 63, n = (i >> 9) & 3;
        int kk = (i >> 11) & 1, w = (i >> 12) & 3, kt = i >> 14;
        int lo = lane & 15, hi = lane >> 4;
        int k = kt * 64 + kk * 32 + hi * 8 + e;
        int col = w * 64 + n * 16 + lo;
        WinF[i] = f2bf(Win[k * 256 + col]);
        return;
    }
    int j = i - 327680;
    if (j < 262144) {
        int g = j >> 16, r = j & 65535;
        int chunk = r >> 9, within = r & 511;
        int lane = within >> 3, e = within & 7;
        int w = chunk >> 5, kk = (chunk >> 2) & 7, n = chunk & 3;
        int lo = lane & 15, hi = lane >> 4;
        int col = w * 64 + n * 16 + lo;
        int k = kk * 32 + hi * 8 + e;
        const float* W = (g == 0) ? W1a : (g == 1) ? W1b : (g == 2) ? W2a : W2b;
        Wfrag[j] = f2bf(W[k * 256 + col]);
        return;
    }
    int z = j - 262144;
    if (z < outN) out[z] = 0.0f;
}

// ---------------------------------------------------------------------------
// fused: 64 edge-rows, 4 waves (wave w -> cols 64w..64w+63). 65KB LDS,
// 2 blocks/CU. Phase 1: BK=128 steps + 2-deep A register prefetch (A(s+2)
// issued at step top into the free va set -> ~1.5 steps of HBM cover).
// Phase 2: 3-set rotating B pipeline (champion, unchanged).
// ---------------------------------------------------------------------------
__global__ __launch_bounds__(256, 2) void fused_kernel(
    const float* __restrict__ A, const u16* __restrict__ WinF,
    const u16* __restrict__ Wfrag, const float* __restrict__ Wout,
    const float* __restrict__ evec, const int* __restrict__ eidx,
    float* __restrict__ out) {
    __shared__ u16 xb[64 * 256];   // 32KB swizzled x tile (512B rows)
    __shared__ u16 tb[64 * 256];   // 32KB temp; = 2x16KB A dbuf in phase 1
    __shared__ float fpart[4][64];
    const int t = threadIdx.x, w = t >> 6, l = t & 63;
    const int lo = l & 15, hi = l >> 4;
    const int swz = (lo & 7) << 4;
    const long rowbase = (long)blockIdx.x * 64;
    char* xbB = (char*)xb;
    char* tbB = (char*)tb;
    char* As0 = tbB;                // 16KB: 64 rows x 256B (128 k bf16)
    char* As1 = tbB + 16384;

    f32x4 acc[4][4];
#pragma unroll
    for (int m = 0; m < 4; m++)
#pragma unroll
        for (int n = 0; n < 4; n++) acc[m][n] = (f32x4){0.f, 0.f, 0.f, 0.f};

    // ---------------- phase 1: x = ssilu(x_cat @ W_in), BK=128 ----------------
    float4 va0[4][2], va1[4][2];   // two A register sets (A(k) -> set k&1)
    auto LOADA = [&](int kb, float4 (&va)[4][2]) {
#pragma unroll
        for (int c = 0; c < 4; ++c) {
            int idx = t + c * 256;
            int r = idx >> 4, k8 = (idx & 15) * 8;
            const float* s = A + (rowbase + r) * 1280 + kb + k8;
            va[c][0] = *(const float4*)s;
            va[c][1] = *(const float4*)(s + 4);
        }
    };
    auto WRITEA = [&](char* dst, const float4 (&va)[4][2]) {
#pragma unroll
        for (int c = 0; c < 4; ++c) {
            int idx = t + c * 256;
            int r = idx >> 4, k8 = (idx & 15) * 8;
            us8 p;
            p[0] = f2bf(va[c][0].x); p[1] = f2bf(va[c][0].y);
            p[2] = f2bf(va[c][0].z); p[3] = f2bf(va[c][0].w);
            p[4] = f2bf(va[c][1].x); p[5] = f2bf(va[c][1].y);
            p[6] = f2bf(va[c][1].z); p[7] = f2bf(va[c][1].w);
            *(us8*)(dst + r * 256 + ((k8 * 2) ^ ((r & 7) << 4))) = p;
        }
    };
    const u16* WinFw = WinF + w * 4096 + l * 8;
    auto LOADB = [&](int kt, bf16x8 (&b)[8]) {
        const u16* base = WinFw + kt * 16384;
#pragma unroll
        for (int kkL = 0; kkL < 2; ++kkL)
#pragma unroll
            for (int n = 0; n < 4; ++n)
                b[kkL * 4 + n] = __builtin_bit_cast(bf16x8,
                    *(const us8*)(base + kkL * 2048 + n * 512));
    };
    auto MFMA_HALF = [&](const char* AB, int half, const bf16x8 (&b)[8]) {
#pragma unroll
        for (int kkL = 0; kkL < 2; ++kkL) {
            int kbyte = (half * 2 + kkL) * 64 + hi * 16;
            bf16x8 af[4];
#pragma unroll
            for (int m = 0; m < 4; m++) {
                int r = m * 16 + lo;
                af[m] = __builtin_bit_cast(bf16x8,
                    *(const us8*)(AB + r * 256 + (kbyte ^ swz)));
            }
#pragma unroll
            for (int m = 0; m < 4; m++)
#pragma unroll
                for (int n = 0; n < 4; n++)
                    acc[m][n] = __builtin_amdgcn_mfma_f32_16x16x32_bf16(
                        af[m], b[kkL * 4 + n], acc[m][n], 0, 0, 0);
        }
    };
    auto FENCE = [&]() {
        asm volatile("s_waitcnt lgkmcnt(0)" ::: "memory");
        __builtin_amdgcn_sched_barrier(0);
        __builtin_amdgcn_s_barrier();
    };

    {
        bf16x8 bc[8], bn[8];

        // prologue: As0 <- A(0) (via va0); va1 <- A(1); bc <- B(tile 0)
        LOADA(0, va0);
        WRITEA(As0, va0);
        LOADB(0, bc);
        LOADA(128, va1);
        FENCE();

        // step s: fill free set with A(s+2) at TOP, consume A(s+1) at WRITEA
        auto STEP = [&](int s, const char* AScur, char* ASnxt,
                        const float4 (&vaCons)[4][2], float4 (&vaFill)[4][2]) {
            const bool more = (s < 9);
            if (s <= 7) LOADA((s + 2) * 128, vaFill);   // ~1.5 steps of cover
            LOADB(2 * s + 1, bn);                 // this step's kk23
            __builtin_amdgcn_sched_barrier(0);
            MFMA_HALF(AScur, 0, bc);              // 32 MFMA
            if (more) LOADB(2 * s + 2, bc);       // next step's kk01
            MFMA_HALF(AScur, 1, bn);              // 32 MFMA
            if (more) WRITEA(ASnxt, vaCons);      // stage A(s+1)
            FENCE();
        };

        for (int i = 0; i < 5; ++i) {
            STEP(2 * i,     As0, As1, va1, va0);
            STEP(2 * i + 1, As1, As0, va0, va1);
        }
    }

    // epilogue: x = ssilu(acc) -> xb (swizzled); tb's A-staging role ends
#pragma unroll
    for (int m = 0; m < 4; m++)
#pragma unroll
        for (int n = 0; n < 4; n++)
#pragma unroll
            for (int j = 0; j < 4; j++) {
                int r = m * 16 + hi * 4 + j;
                int cc = w * 64 + n * 16 + lo;
                *(u16*)(xbB + r * 512 + ((cc * 2) ^ ((r & 7) << 4))) =
                    f2bf(ssilu(acc[m][n][j]));
            }

    // ---------------- phase 2: residual stack, 3-set rotating B ----------
    const u16* Wfw = Wfrag + w * 16384;
    bf16x8 b0[4], b1[4], b2[4];

    auto LW = [&](const u16* Wg, int kk, bf16x8 (&b)[4]) {
        const u16* base = Wg + kk * 2048 + l * 8;
#pragma unroll
        for (int n = 0; n < 4; ++n)
            b[n] = __builtin_bit_cast(bf16x8, *(const us8*)(base + n * 512));
    };
    auto GEMM = [&](const char* AB, const u16* Wg) {
#pragma unroll
        for (int m = 0; m < 4; m++)
#pragma unroll
            for (int n = 0; n < 4; n++) acc[m][n] = (f32x4){0.f, 0.f, 0.f, 0.f};
#pragma unroll
        for (int kk = 0; kk < 8; ++kk) {
            if (kk < 6) {
                const int s = (kk + 2) % 3;
                if (s == 0)      LW(Wg, kk + 2, b0);
                else if (s == 1) LW(Wg, kk + 2, b1);
                else             LW(Wg, kk + 2, b2);
            }
            int kbyte = kk * 64 + hi * 16;
            bf16x8 af[4];
#pragma unroll
            for (int m = 0; m < 4; m++) {
                int r = m * 16 + lo;
                af[m] = __builtin_bit_cast(bf16x8,
                    *(const us8*)(AB + r * 512 + (kbyte ^ ((r & 7) << 4))));
            }
            const bf16x8 (&bu)[4] = (kk % 3 == 0) ? b0 : (kk % 3 == 1) ? b1 : b2;
#pragma unroll
            for (int m = 0; m < 4; m++)
#pragma unroll
                for (int n = 0; n < 4; n++)
                    acc[m][n] = __builtin_amdgcn_mfma_f32_16x16x32_bf16(
                        af[m], bu[n], acc[m][n], 0, 0, 0);
        }
    };

    // G1: t1 = ssilu(x @ W1a) -> tb
    LW(Wfw + 0 * 65536, 0, b0);
    LW(Wfw + 0 * 65536, 1, b1);
    FENCE();
    GEMM(xbB, Wfw + 0 * 65536);
#pragma unroll
    for (int m = 0; m < 4; m++)
#pragma unroll
        for (int n = 0; n < 4; n++)
#pragma unroll
            for (int j = 0; j < 4; j++) {
                int r = m * 16 + hi * 4 + j;
                int cc = w * 64 + n * 16 + lo;
                *(u16*)(tbB + r * 512 + ((cc * 2) ^ ((r & 7) << 4))) =
                    f2bf(ssilu(acc[m][n][j]));
            }
    LW(Wfw + 1 * 65536, 0, b0);
    LW(Wfw + 1 * 65536, 1, b1);
    FENCE();

    // G2: x = (x + ssilu(t1 @ W1b)) * INV_SQRT2 -> xb
    GEMM(tbB, Wfw + 1 * 65536);
#pragma unroll
    for (int m = 0; m < 4; m++)
#pragma unroll
        for (int n = 0; n < 4; n++)
#pragma unroll
            for (int j = 0; j < 4; j++) {
                int r = m * 16 + hi * 4 + j;
                int cc = w * 64 + n * 16 + lo;
                char* p = xbB + r * 512 + ((cc * 2) ^ ((r & 7) << 4));
                float xn = (bf2f(*(u16*)p) + ssilu(acc[m][n][j])) * INV_SQRT2;
                *(u16*)p = f2bf(xn);
            }
    LW(Wfw + 2 * 65536, 0, b0);
    LW(Wfw + 2 * 65536, 1, b1);
    FENCE();

    // G3: t1 = ssilu(x @ W2a) -> tb
    GEMM(xbB, Wfw + 2 * 65536);
#pragma unroll
    for (int m = 0; m < 4; m++)
#pragma unroll
        for (int n = 0; n < 4; n++)
#pragma unroll
            for (int j = 0; j < 4; j++) {
                int r = m * 16 + hi * 4 + j;
                int cc = w * 64 + n * 16 + lo;
                *(u16*)(tbB + r * 512 + ((cc * 2) ^ ((r & 7) << 4))) =
                    f2bf(ssilu(acc[m][n][j]));
            }
    LW(Wfw + 3 * 65536, 0, b0);
    LW(Wfw + 3 * 65536, 1, b1);
    FENCE();

    // G4: x_final = (x + ssilu(t1 @ W2b)) * INV_SQRT2, fp32 in regs
    GEMM(tbB, Wfw + 3 * 65536);
    float wo[4];
#pragma unroll
    for (int n = 0; n < 4; n++) wo[n] = Wout[w * 64 + n * 16 + lo];

    float part[4][4];
#pragma unroll
    for (int m = 0; m < 4; m++)
#pragma unroll
        for (int j = 0; j < 4; j++) part[m][j] = 0.f;
#pragma unroll
    for (int m = 0; m < 4; m++)
#pragma unroll
        for (int n = 0; n < 4; n++)
#pragma unroll
            for (int j = 0; j < 4; j++) {
                int r = m * 16 + hi * 4 + j;
                int cc = w * 64 + n * 16 + lo;
                const char* p = xbB + r * 512 + ((cc * 2) ^ ((r & 7) << 4));
                float xf = (bf2f(*(const u16*)p) + ssilu(acc[m][n][j])) * INV_SQRT2;
                part[m][j] += xf * wo[n];
            }
#pragma unroll
    for (int m = 0; m < 4; m++)
#pragma unroll
        for (int j = 0; j < 4; j++) {
            float v = part[m][j];
            v += __shfl_xor(v, 1);
            v += __shfl_xor(v, 2);
            v += __shfl_xor(v, 4);
            v += __shfl_xor(v, 8);
            if (lo == 0) fpart[w][m * 16 + hi * 4 + j] = v;
        }
    __syncthreads();

    if (t < 64) {
        int r = t;
        float F = fpart[0][r] + fpart[1][r] + fpart[2][r] + fpart[3][r];
        long e = rowbase + r;
        float vx = evec[e * 3 + 0], vy = evec[e * 3 + 1], vz = evec[e * 3 + 2];
        int a = eidx[e];
        atomicAdd(&out[a * 3 + 0], F * vx);
        atomicAdd(&out[a * 3 + 1], F * vy);
        atomicAdd(&out[a * 3 + 2], F * vz);
    }
}

extern "C" void kernel_launch(void* const* d_in, const int* in_sizes, int n_in,
                              void* d_out, int out_size, void* d_ws, size_t ws_size,
                              hipStream_t stream) {
    const float* x_cat = (const float*)d_in[0];
    const float* evec  = (const float*)d_in[1];
    const int*   eidx  = (const int*)d_in[2];
    const float* Win   = (const float*)d_in[3];
    const float* W1a   = (const float*)d_in[4];
    const float* W1b   = (const float*)d_in[5];
    const float* W2a   = (const float*)d_in[6];
    const float* W2b   = (const float*)d_in[7];
    const float* Wout  = (const float*)d_in[8];
    float* out = (float*)d_out;
    const int E = in_sizes[1] / 3;   // 200000

    u16* WinF  = (u16*)d_ws;          // 327680 elems
    u16* Wfrag = WinF + 327680;       // 262144 elems

    int prepN = 327680 + 262144 + out_size;
    prep_kernel<<<(prepN + 255) / 256, 256, 0, stream>>>(
        Win, W1a, W1b, W2a, W2b, WinF, Wfrag, out, out_size);
    fused_kernel<<<E / 64, 256, 0, stream>>>(
        x_cat, WinF, Wfrag, Wout, evec, eidx, out);
}

// Round 16
// 356.308 us; speedup vs baseline: 2.0970x; 1.0577x over previous
//
#include <hip/hip_runtime.h>

typedef __attribute__((ext_vector_type(4))) float f32x4;
typedef __attribute__((ext_vector_type(8))) __bf16 bf16x8;
typedef __attribute__((ext_vector_type(8))) unsigned short us8;
typedef __attribute__((ext_vector_type(4))) unsigned short us4;
typedef unsigned short u16;

#define SSILU_SCALE (1.0f / 0.6f)
#define INV_SQRT2 0.70710678118654752f

__device__ __forceinline__ u16 f2bf(float f) {
    __bf16 h = (__bf16)f;
    return __builtin_bit_cast(u16, h);
}
__device__ __forceinline__ float bf2f(u16 h) {
    union { unsigned int u; float f; } v; v.u = ((unsigned int)h) << 16;
    return v.f;
}
__device__ __forceinline__ float ssilu(float x) {
    float e = __expf(-x);
    float s = __builtin_amdgcn_rcpf(1.0f + e);
    return x * s * SSILU_SCALE;
}

// ---------------------------------------------------------------------------
// prep: (unchanged layouts)
//  WinF : W_in as B-fragments [kt20][w4][kk2][n4][lane64][8]
//  Wfrag: 4 resid matrices as [g][w4][kk8][n4][lane64][8]
// ---------------------------------------------------------------------------
__global__ __launch_bounds__(256) void prep_kernel(
    const float* __restrict__ Win, const float* __restrict__ W1a,
    const float* __restrict__ W1b, const float* __restrict__ W2a,
    const float* __restrict__ W2b, u16* __restrict__ WinF,
    u16* __restrict__ Wfrag, float* __restrict__ out, int outN) {
    int i = blockIdx.x * 256 + threadIdx.x;
    if (i < 327680) {
        int e = i & 7, lane = (i >> 3) & 63, n = (i >> 9) & 3;
        int kk = (i >> 11) & 1, w = (i >> 12) & 3, kt = i >> 14;
        int lo = lane & 15, hi = lane >> 4;
        int k = kt * 64 + kk * 32 + hi * 8 + e;
        int col = w * 64 + n * 16 + lo;
        WinF[i] = f2bf(Win[k * 256 + col]);
        return;
    }
    int j = i - 327680;
    if (j < 262144) {
        int g = j >> 16, r = j & 65535;
        int chunk = r >> 9, within = r & 511;
        int lane = within >> 3, e = within & 7;
        int w = chunk >> 5, kk = (chunk >> 2) & 7, n = chunk & 3;
        int lo = lane & 15, hi = lane >> 4;
        int col = w * 64 + n * 16 + lo;
        int k = kk * 32 + hi * 8 + e;
        const float* W = (g == 0) ? W1a : (g == 1) ? W1b : (g == 2) ? W2a : W2b;
        Wfrag[j] = f2bf(W[k * 256 + col]);
        return;
    }
    int z = j - 262144;
    if (z < outN) out[z] = 0.0f;
}

// ---------------------------------------------------------------------------
// fused: 64 edge-rows, 4 waves. 65KB LDS, 2 blocks/CU.
// SWAPPED-OPERAND MFMA everywhere: acc = mfma(Wfrag, xfrag) = (x@W)^T, so
// acc[m][n][j] maps to row = m*16+lo, col = w*64+n*16+hi*4+j -> the 4 j's
// are 8 contiguous bytes in the row-major swizzled LDS tile => all
// epilogue LDS traffic is packed b64 (4x fewer LDS ops than R15).
// Phase 1: BK=128 + 2-deep A reg prefetch (R15). Phase 2: 3-set rotating B.
// ---------------------------------------------------------------------------
__global__ __launch_bounds__(256, 2) void fused_kernel(
    const float* __restrict__ A, const u16* __restrict__ WinF,
    const u16* __restrict__ Wfrag, const float* __restrict__ Wout,
    const float* __restrict__ evec, const int* __restrict__ eidx,
    float* __restrict__ out) {
    __shared__ u16 xb[64 * 256];   // 32KB swizzled x tile (512B rows)
    __shared__ u16 tb[64 * 256];   // 32KB temp; = 2x16KB A dbuf in phase 1
    __shared__ float fpart[4][64];
    const int t = threadIdx.x, w = t >> 6, l = t & 63;
    const int lo = l & 15, hi = l >> 4;
    const int swz = (lo & 7) << 4;
    const long rowbase = (long)blockIdx.x * 64;
    char* xbB = (char*)xb;
    char* tbB = (char*)tb;
    char* As0 = tbB;                // 16KB: 64 rows x 256B (128 k bf16)
    char* As1 = tbB + 16384;

    f32x4 acc[4][4];
#pragma unroll
    for (int m = 0; m < 4; m++)
#pragma unroll
        for (int n = 0; n < 4; n++) acc[m][n] = (f32x4){0.f, 0.f, 0.f, 0.f};

    // byte offset of acc[m][n]'s 4-elem run in a [row][col] swizzled tile
    auto RUNOFF = [&](int m, int n) {
        int row = m * 16 + lo;
        int colb = (w * 64 + n * 16 + hi * 4) * 2;
        return row * 512 + (colb ^ ((row & 7) << 4));
    };

    // ---------------- phase 1: x = ssilu(x_cat @ W_in), BK=128 ----------------
    float4 va0[4][2], va1[4][2];   // two A register sets (A(k) -> set k&1)
    auto LOADA = [&](int kb, float4 (&va)[4][2]) {
#pragma unroll
        for (int c = 0; c < 4; ++c) {
            int idx = t + c * 256;
            int r = idx >> 4, k8 = (idx & 15) * 8;
            const float* s = A + (rowbase + r) * 1280 + kb + k8;
            va[c][0] = *(const float4*)s;
            va[c][1] = *(const float4*)(s + 4);
        }
    };
    auto WRITEA = [&](char* dst, const float4 (&va)[4][2]) {
#pragma unroll
        for (int c = 0; c < 4; ++c) {
            int idx = t + c * 256;
            int r = idx >> 4, k8 = (idx & 15) * 8;
            us8 p;
            p[0] = f2bf(va[c][0].x); p[1] = f2bf(va[c][0].y);
            p[2] = f2bf(va[c][0].z); p[3] = f2bf(va[c][0].w);
            p[4] = f2bf(va[c][1].x); p[5] = f2bf(va[c][1].y);
            p[6] = f2bf(va[c][1].z); p[7] = f2bf(va[c][1].w);
            *(us8*)(dst + r * 256 + ((k8 * 2) ^ ((r & 7) << 4))) = p;
        }
    };
    const u16* WinFw = WinF + w * 4096 + l * 8;
    auto LOADB = [&](int kt, bf16x8 (&b)[8]) {
        const u16* base = WinFw + kt * 16384;
#pragma unroll
        for (int kkL = 0; kkL < 2; ++kkL)
#pragma unroll
            for (int n = 0; n < 4; ++n)
                b[kkL * 4 + n] = __builtin_bit_cast(bf16x8,
                    *(const us8*)(base + kkL * 2048 + n * 512));
    };
    auto MFMA_HALF = [&](const char* AB, int half, const bf16x8 (&b)[8]) {
#pragma unroll
        for (int kkL = 0; kkL < 2; ++kkL) {
            int kbyte = (half * 2 + kkL) * 64 + hi * 16;
            bf16x8 af[4];
#pragma unroll
            for (int m = 0; m < 4; m++) {
                int r = m * 16 + lo;
                af[m] = __builtin_bit_cast(bf16x8,
                    *(const us8*)(AB + r * 256 + (kbyte ^ swz)));
            }
#pragma unroll
            for (int m = 0; m < 4; m++)
#pragma unroll
                for (int n = 0; n < 4; n++)
                    acc[m][n] = __builtin_amdgcn_mfma_f32_16x16x32_bf16(
                        b[kkL * 4 + n], af[m], acc[m][n], 0, 0, 0);   // swapped
        }
    };
    auto FENCE = [&]() {
        asm volatile("s_waitcnt lgkmcnt(0)" ::: "memory");
        __builtin_amdgcn_sched_barrier(0);
        __builtin_amdgcn_s_barrier();
    };

    {
        bf16x8 bc[8], bn[8];

        // prologue: As0 <- A(0) (via va0); va1 <- A(1); bc <- B(tile 0)
        LOADA(0, va0);
        WRITEA(As0, va0);
        LOADB(0, bc);
        LOADA(128, va1);
        FENCE();

        auto STEP = [&](int s, const char* AScur, char* ASnxt,
                        const float4 (&vaCons)[4][2], float4 (&vaFill)[4][2]) {
            const bool more = (s < 9);
            if (s <= 7) LOADA((s + 2) * 128, vaFill);   // ~1.5 steps of cover
            LOADB(2 * s + 1, bn);
            __builtin_amdgcn_sched_barrier(0);
            MFMA_HALF(AScur, 0, bc);
            if (more) LOADB(2 * s + 2, bc);
            MFMA_HALF(AScur, 1, bn);
            if (more) WRITEA(ASnxt, vaCons);
            FENCE();
        };

        for (int i = 0; i < 5; ++i) {
            STEP(2 * i,     As0, As1, va1, va0);
            STEP(2 * i + 1, As1, As0, va0, va1);
        }
    }

    // epilogue: x = ssilu(acc) -> xb, packed b64 (row = m*16+lo)
#pragma unroll
    for (int m = 0; m < 4; m++)
#pragma unroll
        for (int n = 0; n < 4; n++) {
            us4 p;
#pragma unroll
            for (int j = 0; j < 4; j++) p[j] = f2bf(ssilu(acc[m][n][j]));
            *(us4*)(xbB + RUNOFF(m, n)) = p;
        }

    // ---------------- phase 2: residual stack, 3-set rotating B ----------
    const u16* Wfw = Wfrag + w * 16384;
    bf16x8 b0[4], b1[4], b2[4];

    auto LW = [&](const u16* Wg, int kk, bf16x8 (&b)[4]) {
        const u16* base = Wg + kk * 2048 + l * 8;
#pragma unroll
        for (int n = 0; n < 4; ++n)
            b[n] = __builtin_bit_cast(bf16x8, *(const us8*)(base + n * 512));
    };
    auto GEMM = [&](const char* AB, const u16* Wg) {
#pragma unroll
        for (int m = 0; m < 4; m++)
#pragma unroll
            for (int n = 0; n < 4; n++) acc[m][n] = (f32x4){0.f, 0.f, 0.f, 0.f};
#pragma unroll
        for (int kk = 0; kk < 8; ++kk) {
            if (kk < 6) {
                const int s = (kk + 2) % 3;
                if (s == 0)      LW(Wg, kk + 2, b0);
                else if (s == 1) LW(Wg, kk + 2, b1);
                else             LW(Wg, kk + 2, b2);
            }
            int kbyte = kk * 64 + hi * 16;
            bf16x8 af[4];
#pragma unroll
            for (int m = 0; m < 4; m++) {
                int r = m * 16 + lo;
                af[m] = __builtin_bit_cast(bf16x8,
                    *(const us8*)(AB + r * 512 + (kbyte ^ ((r & 7) << 4))));
            }
            const bf16x8 (&bu)[4] = (kk % 3 == 0) ? b0 : (kk % 3 == 1) ? b1 : b2;
#pragma unroll
            for (int m = 0; m < 4; m++)
#pragma unroll
                for (int n = 0; n < 4; n++)
                    acc[m][n] = __builtin_amdgcn_mfma_f32_16x16x32_bf16(
                        bu[n], af[m], acc[m][n], 0, 0, 0);   // swapped
        }
    };

    // G1: t1 = ssilu(x @ W1a) -> tb
    LW(Wfw + 0 * 65536, 0, b0);
    LW(Wfw + 0 * 65536, 1, b1);
    FENCE();
    GEMM(xbB, Wfw + 0 * 65536);
#pragma unroll
    for (int m = 0; m < 4; m++)
#pragma unroll
        for (int n = 0; n < 4; n++) {
            us4 p;
#pragma unroll
            for (int j = 0; j < 4; j++) p[j] = f2bf(ssilu(acc[m][n][j]));
            *(us4*)(tbB + RUNOFF(m, n)) = p;
        }
    LW(Wfw + 1 * 65536, 0, b0);
    LW(Wfw + 1 * 65536, 1, b1);
    FENCE();

    // G2: x = (x + ssilu(t1 @ W1b)) * INV_SQRT2 -> xb (packed rmw)
    GEMM(tbB, Wfw + 1 * 65536);
#pragma unroll
    for (int m = 0; m < 4; m++)
#pragma unroll
        for (int n = 0; n < 4; n++) {
            char* p = xbB + RUNOFF(m, n);
            us4 xv = *(const us4*)p;
            us4 o;
#pragma unroll
            for (int j = 0; j < 4; j++)
                o[j] = f2bf((bf2f(xv[j]) + ssilu(acc[m][n][j])) * INV_SQRT2);
            *(us4*)p = o;
        }
    LW(Wfw + 2 * 65536, 0, b0);
    LW(Wfw + 2 * 65536, 1, b1);
    FENCE();

    // G3: t1 = ssilu(x @ W2a) -> tb
    GEMM(xbB, Wfw + 2 * 65536);
#pragma unroll
    for (int m = 0; m < 4; m++)
#pragma unroll
        for (int n = 0; n < 4; n++) {
            us4 p;
#pragma unroll
            for (int j = 0; j < 4; j++) p[j] = f2bf(ssilu(acc[m][n][j]));
            *(us4*)(tbB + RUNOFF(m, n)) = p;
        }
    LW(Wfw + 3 * 65536, 0, b0);
    LW(Wfw + 3 * 65536, 1, b1);
    FENCE();

    // G4: x_final = (x + ssilu(t1 @ W2b)) * INV_SQRT2, dot W_out
    GEMM(tbB, Wfw + 3 * 65536);
    float wo2[4][4];
#pragma unroll
    for (int n = 0; n < 4; n++)
#pragma unroll
        for (int j = 0; j < 4; j++)
            wo2[n][j] = Wout[w * 64 + n * 16 + hi * 4 + j];

    float part[4];
#pragma unroll
    for (int m = 0; m < 4; m++) part[m] = 0.f;
#pragma unroll
    for (int m = 0; m < 4; m++)
#pragma unroll
        for (int n = 0; n < 4; n++) {
            const char* p = xbB + RUNOFF(m, n);
            us4 xv = *(const us4*)p;
#pragma unroll
            for (int j = 0; j < 4; j++) {
                float xf = (bf2f(xv[j]) + ssilu(acc[m][n][j])) * INV_SQRT2;
                part[m] += xf * wo2[n][j];
            }
        }
    // reduce over hi (lanes l, l^16, l^32): every lane ends with its row sum
#pragma unroll
    for (int m = 0; m < 4; m++) {
        float v = part[m];
        v += __shfl_xor(v, 16);
        v += __shfl_xor(v, 32);
        if (hi == 0) fpart[w][m * 16 + lo] = v;
    }
    __syncthreads();

    if (t < 64) {
        int r = t;
        float F = fpart[0][r] + fpart[1][r] + fpart[2][r] + fpart[3][r];
        long e = rowbase + r;
        float vx = evec[e * 3 + 0], vy = evec[e * 3 + 1], vz = evec[e * 3 + 2];
        int a = eidx[e];
        atomicAdd(&out[a * 3 + 0], F * vx);
        atomicAdd(&out[a * 3 + 1], F * vy);
        atomicAdd(&out[a * 3 + 2], F * vz);
    }
}

extern "C" void kernel_launch(void* const* d_in, const int* in_sizes, int n_in,
                              void* d_out, int out_size, void* d_ws, size_t ws_size,
                              hipStream_t stream) {
    const float* x_cat = (const float*)d_in[0];
    const float* evec  = (const float*)d_in[1];
    const int*   eidx  = (const int*)d_in[2];
    const float* Win   = (const float*)d_in[3];
    const float* W1a   = (const float*)d_in[4];
    const float* W1b   = (const float*)d_in[5];
    const float* W2a   = (const float*)d_in[6];
    const float* W2b   = (const float*)d_in[7];
    const float* Wout  = (const float*)d_in[8];
    float* out = (float*)d_out;
    const int E = in_sizes[1] / 3;   // 200000

    u16* WinF  = (u16*)d_ws;          // 327680 elems
    u16* Wfrag = WinF + 327680;       // 262144 elems

    int prepN = 327680 + 262144 + out_size;
    prep_kernel<<<(prepN + 255) / 256, 256, 0, stream>>>(
        Win, W1a, W1b, W2a, W2b, WinF, Wfrag, out, out_size);
    fused_kernel<<<E / 64, 256, 0, stream>>>(
        x_cat, WinF, Wfrag, Wout, evec, eidx, out);
}